// Round 1
// baseline (805.117 us; speedup 1.0000x reference)
//
#include <hip/hip_runtime.h>
#include <hip/hip_bf16.h>

#define B_  64
#define T_  512
#define H_  1024
#define HC  512     // H/2
#define L9  9
#define M_  32768   // B*T

typedef short short8 __attribute__((ext_vector_type(8)));
typedef float f32x4 __attribute__((ext_vector_type(4)));

__device__ __forceinline__ unsigned short f2bf(float x) {
  unsigned u = __float_as_uint(x);
  u += 0x7FFFu + ((u >> 16) & 1u);   // RTNE
  return (unsigned short)(u >> 16);
}
__device__ __forceinline__ float bf2f(unsigned short h) {
  return __uint_as_float(((unsigned)h) << 16);
}

// ---------------- init logits with b2 broadcast ----------------
__global__ void init_logits(float* __restrict__ out, const float* __restrict__ b2) {
  int i = blockIdx.x * 256 + threadIdx.x;   // 294912 exact
  int l = i % 9;
  out[i] = b2[l];
}

// ---------------- fused GEMM: logits += relu(hs@W1+b1) @ W2seg ----------------
__global__ __launch_bounds__(256) void gemm_fused(
    const float* __restrict__ hs, const float* __restrict__ w1,
    const float* __restrict__ b1, const float* __restrict__ w2,
    float* __restrict__ logits)
{
  __shared__ __align__(16) char smem[36864 + 4608];
  unsigned short* ldsA = (unsigned short*)smem;            // [128][72] bf16
  unsigned short* ldsB = (unsigned short*)(smem + 18432);  // [128 col][72 k] bf16
  unsigned short* ldsX = (unsigned short*)smem;            // [128 col][136 row] bf16 (reuse)
  float* ldsW2 = (float*)(smem + 36864);                   // [128*9]

  const int tid  = threadIdx.x;
  const int lane = tid & 63;
  const int wid  = tid >> 6;
  const int wr = wid >> 1, wc = wid & 1;
  const int mblk = blockIdx.x >> 2, nblk = blockIdx.x & 3;
  const int row0 = mblk * 128;
  const int n0   = nblk * 128;

  for (int i = tid; i < 1152; i += 256) ldsW2[i] = w2[n0 * 9 + i];

  f32x4 acc[4][4];
  #pragma unroll
  for (int a = 0; a < 4; ++a)
    #pragma unroll
    for (int b = 0; b < 4; ++b) acc[a][b] = (f32x4){0.f, 0.f, 0.f, 0.f};

  for (int kt = 0; kt < 16; ++kt) {
    const int k0 = kt * 64;
    __syncthreads();
    // stage A tile 128x64 fp32 -> bf16 (coalesced float4 reads)
    #pragma unroll
    for (int i = 0; i < 8; ++i) {
      int idx = i * 256 + tid;
      int r = idx >> 4, c4 = idx & 15;
      float4 v = *(const float4*)(hs + (row0 + r) * H_ + k0 + c4 * 4);
      uint2 d;
      d.x = (unsigned)f2bf(v.x) | ((unsigned)f2bf(v.y) << 16);
      d.y = (unsigned)f2bf(v.z) | ((unsigned)f2bf(v.w) << 16);
      *(uint2*)(ldsA + r * 72 + c4 * 4) = d;
    }
    // stage B tile 64x128, transposed to [n][k] (per-instr coalesced dword reads)
    #pragma unroll
    for (int i = 0; i < 8; ++i) {
      int idx = i * 256 + tid;
      int n = idx & 127, kq = idx >> 7;
      const float* src = w1 + (k0 + kq * 4) * HC + n0 + n;
      float x0 = src[0];
      float x1 = src[HC];
      float x2 = src[2 * HC];
      float x3 = src[3 * HC];
      uint2 d;
      d.x = (unsigned)f2bf(x0) | ((unsigned)f2bf(x1) << 16);
      d.y = (unsigned)f2bf(x2) | ((unsigned)f2bf(x3) << 16);
      *(uint2*)(ldsB + n * 72 + kq * 4) = d;
    }
    __syncthreads();
    #pragma unroll
    for (int ks = 0; ks < 2; ++ks) {
      const int kk = ks * 32 + (lane >> 4) * 8;
      short8 aF[4], bF[4];
      #pragma unroll
      for (int mi = 0; mi < 4; ++mi)
        aF[mi] = *(const short8*)(ldsA + (wr * 64 + mi * 16 + (lane & 15)) * 72 + kk);
      #pragma unroll
      for (int ni = 0; ni < 4; ++ni)
        bF[ni] = *(const short8*)(ldsB + (wc * 64 + ni * 16 + (lane & 15)) * 72 + kk);
      #pragma unroll
      for (int mi = 0; mi < 4; ++mi)
        #pragma unroll
        for (int ni = 0; ni < 4; ++ni)
          acc[mi][ni] = __builtin_amdgcn_mfma_f32_16x16x32_bf16(aF[mi], bF[ni], acc[mi][ni], 0, 0, 0);
    }
  }
  __syncthreads();
  // epilogue: +b1, relu, bf16, store transposed x^T[col][row]
  float b1v[4];
  #pragma unroll
  for (int ni = 0; ni < 4; ++ni) b1v[ni] = b1[n0 + wc * 64 + ni * 16 + (lane & 15)];
  #pragma unroll
  for (int mi = 0; mi < 4; ++mi) {
    int rbase = wr * 64 + mi * 16 + (lane >> 4) * 4;
    #pragma unroll
    for (int ni = 0; ni < 4; ++ni) {
      int col = wc * 64 + ni * 16 + (lane & 15);
      unsigned short q[4];
      #pragma unroll
      for (int qq = 0; qq < 4; ++qq) {
        float v = acc[mi][ni][qq] + b1v[ni];
        q[qq] = f2bf(fmaxf(v, 0.f));
      }
      uint2 d;
      d.x = (unsigned)q[0] | ((unsigned)q[1] << 16);
      d.y = (unsigned)q[2] | ((unsigned)q[3] << 16);
      *(uint2*)(ldsX + col * 136 + rbase) = d;
    }
  }
  __syncthreads();
  // phase 2: partial logits (x-tile @ W2seg) -> atomicAdd
  {
    int r = tid & 127, ch = tid >> 7;
    float s[9];
    #pragma unroll
    for (int l = 0; l < 9; ++l) s[l] = 0.f;
    for (int c = ch * 64; c < ch * 64 + 64; ++c) {
      float xv = bf2f(ldsX[c * 136 + r]);
      const float* wrow = ldsW2 + c * 9;
      #pragma unroll
      for (int l = 0; l < 9; ++l) s[l] += xv * wrow[l];
    }
    float* dst = logits + (row0 + r) * 9;
    #pragma unroll
    for (int l = 0; l < 9; ++l) atomicAdd(dst + l, s[l]);
  }
}

// ---------------- transpose + exponentiate emissions: wsE[t][j][b] ----------------
__global__ void prep_exp(const float* __restrict__ logits, float* __restrict__ wsE) {
  int i = blockIdx.x * 256 + threadIdx.x;  // 294912 exact
  int b = i & 63;
  int tj = i >> 6;          // t*9 + j
  int t = tj / 9;
  int j = tj - t * 9;
  wsE[i] = __expf(logits[b * (T_ * 9) + t * 9 + j]);
}

// ---------------- tags+mask pack: wsTag[t][b] = ctag | (mask<<8) ----------------
__global__ void prep_tag(const int* __restrict__ labels, const int* __restrict__ amask,
                         unsigned* __restrict__ wsTag) {
  int i = blockIdx.x * 256 + threadIdx.x;  // 32768 exact; i = t*64+b
  int b = i & 63, t = i >> 6;
  int lab = labels[b * T_ + t];
  int am  = amask[b * T_ + t];
  int valid = (lab != -100) ? 1 : 0;
  int ctag  = valid ? lab : 0;
  int m = ((am != 0) && valid) ? 1 : 0;
  if (t == 0) m = 1;
  wsTag[i] = (unsigned)ctag | ((unsigned)m << 8);
}

// ---------------- CRF loss: scaled forward (exp-domain) + gold path ----------------
__global__ void crf_loss(const float* __restrict__ wsE, const unsigned* __restrict__ wsTag,
                         const float* __restrict__ start_t, const float* __restrict__ end_t,
                         const float* __restrict__ trans, float* __restrict__ out_loss)
{
  __shared__ float sTrans[81];
  int b = threadIdx.x;  // 64 threads, lane = batch
  for (int i = b; i < 81; i += 64) sTrans[i] = trans[i];
  __syncthreads();
  float eT[81];
  #pragma unroll
  for (int i = 0; i < 81; ++i) eT[i] = __expf(sTrans[i]);
  float eEnd[9];
  #pragma unroll
  for (int j = 0; j < 9; ++j) eEnd[j] = __expf(end_t[j]);

  float P[9];
  #pragma unroll
  for (int j = 0; j < 9; ++j) P[j] = __expf(start_t[j]) * wsE[j * 64 + b];
  float mx = P[0];
  #pragma unroll
  for (int j = 1; j < 9; ++j) mx = fmaxf(mx, P[j]);
  float C = __logf(mx);
  float inv = 1.0f / mx;
  #pragma unroll
  for (int j = 0; j < 9; ++j) P[j] *= inv;

  unsigned tv0 = wsTag[b];
  int prev = (int)(tv0 & 255u);
  float num = start_t[prev] + __logf(wsE[prev * 64 + b]);

  for (int t = 1; t < T_; ++t) {
    float E[9];
    #pragma unroll
    for (int j = 0; j < 9; ++j) E[j] = wsE[(t * 9 + j) * 64 + b];
    unsigned tv = wsTag[t * 64 + b];
    int  ctag = (int)(tv & 255u);
    bool m = ((tv >> 8) & 1u) != 0u;

    float S[9];
    #pragma unroll
    for (int j = 0; j < 9; ++j) {
      float s = 0.f;
      #pragma unroll
      for (int i = 0; i < 9; ++i) s = fmaf(P[i], eT[i * 9 + j], s);
      S[j] = s * E[j];
    }
    float mxs = S[0];
    #pragma unroll
    for (int j = 1; j < 9; ++j) mxs = fmaxf(mxs, S[j]);
    float lg = __logf(mxs);
    float rv = 1.0f / mxs;
    #pragma unroll
    for (int j = 0; j < 9; ++j) P[j] = m ? S[j] * rv : P[j];
    C += m ? lg : 0.f;

    float Es = E[0];
    Es = (ctag == 1) ? E[1] : Es;
    Es = (ctag == 2) ? E[2] : Es;
    Es = (ctag == 3) ? E[3] : Es;
    Es = (ctag == 4) ? E[4] : Es;
    Es = (ctag == 5) ? E[5] : Es;
    Es = (ctag == 6) ? E[6] : Es;
    Es = (ctag == 7) ? E[7] : Es;
    Es = (ctag == 8) ? E[8] : Es;
    float trv = sTrans[prev * 9 + ctag];
    num += m ? (trv + __logf(Es)) : 0.f;
    prev = m ? ctag : prev;
  }
  float sfin = 0.f;
  #pragma unroll
  for (int j = 0; j < 9; ++j) sfin = fmaf(P[j], eEnd[j], sfin);
  float den = C + __logf(sfin);
  num += end_t[prev];
  float d = num - den;
  #pragma unroll
  for (int off = 32; off > 0; off >>= 1) d += __shfl_down(d, off);
  if (b == 0) out_loss[0] = -d * (1.0f / 64.0f);
}

extern "C" void kernel_launch(void* const* d_in, const int* in_sizes, int n_in,
                              void* d_out, int out_size, void* d_ws, size_t ws_size,
                              hipStream_t stream) {
  const float* hs     = (const float*)d_in[0];
  const int*   am     = (const int*)  d_in[1];
  const int*   labels = (const int*)  d_in[2];
  const float* w1     = (const float*)d_in[3];
  const float* b1     = (const float*)d_in[4];
  const float* w2     = (const float*)d_in[5];
  const float* b2     = (const float*)d_in[6];
  const float* st     = (const float*)d_in[7];
  const float* en     = (const float*)d_in[8];
  const float* tr     = (const float*)d_in[9];
  float* out = (float*)d_out;

  float*    wsE   = (float*)d_ws;                            // 294912 f32
  unsigned* wsTag = (unsigned*)((char*)d_ws + 294912 * 4);   // 32768 u32

  init_logits<<<1152, 256, 0, stream>>>(out, b2);
  gemm_fused <<<1024, 256, 0, stream>>>(hs, w1, b1, w2, out);
  prep_exp   <<<1152, 256, 0, stream>>>(out, wsE);
  prep_tag   <<<128,  256, 0, stream>>>(labels, am, wsTag);
  crf_loss   <<<1,    64,  0, stream>>>(wsE, wsTag, st, en, tr, out + 294912);
}

// Round 2
// 578.561 us; speedup vs baseline: 1.3916x; 1.3916x over previous
//
#include <hip/hip_runtime.h>
#include <hip/hip_bf16.h>

#define B_  64
#define T_  512
#define H_  1024
#define HC  512
#define L9  9

typedef short short8 __attribute__((ext_vector_type(8)));
typedef float f32x16 __attribute__((ext_vector_type(16)));

__device__ __forceinline__ unsigned short f2bf(float x) {
  unsigned u = __float_as_uint(x);
  u += 0x7FFFu + ((u >> 16) & 1u);   // RTNE
  return (unsigned short)(u >> 16);
}
__device__ __forceinline__ float bf2f(unsigned short h) {
  return __uint_as_float(((unsigned)h) << 16);
}

__device__ __forceinline__ void gload_lds16(const void* g, void* l) {
  __builtin_amdgcn_global_load_lds((const __attribute__((address_space(1))) unsigned*)g,
                                   (__attribute__((address_space(3))) unsigned*)l, 16, 0, 0);
}

// ---------- w1 [1024][512] fp32 -> wsBn [512][1024] bf16 (transposed) ----------
__global__ void conv_w1(const float* __restrict__ w1, unsigned short* __restrict__ w1b) {
  int idx = blockIdx.x * 256 + threadIdx.x;   // 131072 exact
  int n = idx & 511, kq = idx >> 9;           // kq 0..255
  float x0 = w1[(kq * 4 + 0) * HC + n];
  float x1 = w1[(kq * 4 + 1) * HC + n];
  float x2 = w1[(kq * 4 + 2) * HC + n];
  float x3 = w1[(kq * 4 + 3) * HC + n];
  uint2 d;
  d.x = (unsigned)f2bf(x0) | ((unsigned)f2bf(x1) << 16);
  d.y = (unsigned)f2bf(x2) | ((unsigned)f2bf(x3) << 16);
  *(uint2*)(w1b + n * 1024 + kq * 4) = d;
}

// ---------- tags+mask pack: wsTag[t][b] = ctag | (mask<<8) ----------
__global__ void prep_tag(const int* __restrict__ labels, const int* __restrict__ amask,
                         unsigned* __restrict__ wsTag) {
  int i = blockIdx.x * 256 + threadIdx.x;  // 32768 exact; i = t*64+b
  int b = i & 63, t = i >> 6;
  int lab = labels[b * T_ + t];
  int am  = amask[b * T_ + t];
  int valid = (lab != -100) ? 1 : 0;
  int ctag  = valid ? lab : 0;
  int m = ((am != 0) && valid) ? 1 : 0;
  if (t == 0) m = 1;
  wsTag[i] = (unsigned)ctag | ((unsigned)m << 8);
}

// ---------- fused GEMM: BM=64, BN=512(full), BK=64, 4 waves, 32x32x16 MFMA ----------
// epilogue: x=relu(.+b1) -> LDS, then x@W2+b2 -> logits (d_out) and exp -> wsE
__global__ __launch_bounds__(256, 2) void gemm1(
    const float* __restrict__ hs, const unsigned short* __restrict__ w1b,
    const float* __restrict__ b1, const float* __restrict__ w2,
    const float* __restrict__ b2, float* __restrict__ logits, float* __restrict__ wsE)
{
  __shared__ __align__(16) unsigned char smem[80128];
  unsigned short* ldsA = (unsigned short*)smem;            // [64][64] bf16 swizzled (8 KB)
  unsigned short* ldsB = (unsigned short*)(smem + 8192);   // [512][64] bf16 swizzled (64 KB)

  const int tid  = threadIdx.x;
  const int lane = tid & 63;
  const int w    = tid >> 6;              // wave id = wc (0..3)
  const int row0 = blockIdx.x * 64;

  f32x16 acc[2][4];
  #pragma unroll
  for (int m = 0; m < 2; ++m)
    #pragma unroll
    for (int n = 0; n < 4; ++n)
      #pragma unroll
      for (int e = 0; e < 16; ++e) acc[m][n][e] = 0.f;

  // A staging map: thread -> (row, 16-float chunk)
  const int arow = tid >> 2;
  const int aj4  = tid & 3;
  const float* aSrc = hs + (size_t)(row0 + arow) * H_ + aj4 * 16;
  unsigned short* aDst0 = ldsA + arow * 64 + (((aj4 * 2 + 0) ^ (arow & 7)) * 8);
  unsigned short* aDst1 = ldsA + arow * 64 + (((aj4 * 2 + 1) ^ (arow & 7)) * 8);

  // B staging map (pre-swizzled source, linear LDS dest)
  const int bn   = lane >> 3;                       // 0..7 row-in-chunk
  const int bjsw = ((lane & 7) ^ bn) * 8;           // swizzled source k-offset (elems)

  for (int kt = 0; kt < 16; ++kt) {
    const int k0 = kt * 64;
    // A: fp32 load -> bf16 -> swizzled ds_write
    float4 v0 = *(const float4*)(aSrc + k0);
    float4 v1 = *(const float4*)(aSrc + k0 + 4);
    float4 v2 = *(const float4*)(aSrc + k0 + 8);
    float4 v3 = *(const float4*)(aSrc + k0 + 12);
    uint4 p0, p1;
    p0.x = (unsigned)f2bf(v0.x) | ((unsigned)f2bf(v0.y) << 16);
    p0.y = (unsigned)f2bf(v0.z) | ((unsigned)f2bf(v0.w) << 16);
    p0.z = (unsigned)f2bf(v1.x) | ((unsigned)f2bf(v1.y) << 16);
    p0.w = (unsigned)f2bf(v1.z) | ((unsigned)f2bf(v1.w) << 16);
    p1.x = (unsigned)f2bf(v2.x) | ((unsigned)f2bf(v2.y) << 16);
    p1.y = (unsigned)f2bf(v2.z) | ((unsigned)f2bf(v2.w) << 16);
    p1.z = (unsigned)f2bf(v3.x) | ((unsigned)f2bf(v3.y) << 16);
    p1.w = (unsigned)f2bf(v3.z) | ((unsigned)f2bf(v3.w) << 16);
    *(uint4*)aDst0 = p0;
    *(uint4*)aDst1 = p1;
    // B: async global->LDS, 16 chunks of 1KB per wave
    #pragma unroll
    for (int i = 0; i < 16; ++i) {
      int cc = w * 16 + i;
      gload_lds16(w1b + (size_t)(cc * 8 + bn) * 1024 + k0 + bjsw,
                  (unsigned char*)ldsB + cc * 1024);
    }
    __syncthreads();
    #pragma unroll
    for (int ks = 0; ks < 4; ++ks) {
      const int blk = (((ks * 2 + (lane >> 5)) ^ (lane & 7)) * 8);
      short8 aF[2], bF[4];
      #pragma unroll
      for (int m = 0; m < 2; ++m)
        aF[m] = *(const short8*)(ldsA + (m * 32 + (lane & 31)) * 64 + blk);
      #pragma unroll
      for (int n = 0; n < 4; ++n)
        bF[n] = *(const short8*)(ldsB + (w * 128 + n * 32 + (lane & 31)) * 64 + blk);
      #pragma unroll
      for (int m = 0; m < 2; ++m)
        #pragma unroll
        for (int n = 0; n < 4; ++n)
          acc[m][n] = __builtin_amdgcn_mfma_f32_32x32x16_bf16(aF[m], bF[n], acc[m][n], 0, 0, 0);
    }
    __syncthreads();
  }

  // ---- epilogue: x = relu(acc + b1) -> LDS X [512 col][64 row] bf16, XOR-swizzled ----
  float b1v[4];
  #pragma unroll
  for (int n = 0; n < 4; ++n) b1v[n] = b1[w * 128 + n * 32 + (lane & 31)];

  #pragma unroll
  for (int m = 0; m < 2; ++m)
    #pragma unroll
    for (int n = 0; n < 4; ++n) {
      int col = w * 128 + n * 32 + (lane & 31);
      int csw = col & 7;
      unsigned char* cbase = smem + col * 128 + (lane >> 5) * 8;
      #pragma unroll
      for (int q = 0; q < 4; ++q) {
        unsigned short h0 = f2bf(fmaxf(acc[m][n][q * 4 + 0] + b1v[n], 0.f));
        unsigned short h1 = f2bf(fmaxf(acc[m][n][q * 4 + 1] + b1v[n], 0.f));
        unsigned short h2 = f2bf(fmaxf(acc[m][n][q * 4 + 2] + b1v[n], 0.f));
        unsigned short h3 = f2bf(fmaxf(acc[m][n][q * 4 + 3] + b1v[n], 0.f));
        uint2 d;
        d.x = (unsigned)h0 | ((unsigned)h1 << 16);
        d.y = (unsigned)h2 | ((unsigned)h3 << 16);
        *(uint2*)(cbase + (((4 * m + q) ^ csw) * 16)) = d;
      }
    }

  // W2 -> LDS bf16 [512][12], zero sAcc
  unsigned short* ldsW2 = (unsigned short*)(smem + 65536);
  float* sAcc = (float*)(smem + 77824);   // [64][9]
  {
    int c0 = tid * 2;
    #pragma unroll
    for (int cc = c0; cc < c0 + 2; ++cc)
      #pragma unroll
      for (int l = 0; l < 9; ++l) ldsW2[cc * 12 + l] = f2bf(w2[cc * 9 + l]);
    for (int i = tid; i < 576; i += 256) sAcc[i] = 0.f;
  }
  __syncthreads();

  // partial x@W2 per (row, col-chunk)
  {
    int r = tid & 63, ch = tid >> 6;
    int rblk = r >> 3, rlow = r & 7;
    float s[9];
    #pragma unroll
    for (int l = 0; l < 9; ++l) s[l] = 0.f;
    for (int c = ch * 128; c < ch * 128 + 128; ++c) {
      float xv = bf2f(*(const unsigned short*)(smem + c * 128 + ((rblk ^ (c & 7)) * 16) + rlow * 2));
      uint2 wa = *(const uint2*)(ldsW2 + c * 12);
      uint2 wb = *(const uint2*)(ldsW2 + c * 12 + 4);
      unsigned wcv = *(const unsigned*)(ldsW2 + c * 12 + 8);
      s[0] = fmaf(xv, __uint_as_float(wa.x << 16), s[0]);
      s[1] = fmaf(xv, __uint_as_float(wa.x & 0xFFFF0000u), s[1]);
      s[2] = fmaf(xv, __uint_as_float(wa.y << 16), s[2]);
      s[3] = fmaf(xv, __uint_as_float(wa.y & 0xFFFF0000u), s[3]);
      s[4] = fmaf(xv, __uint_as_float(wb.x << 16), s[4]);
      s[5] = fmaf(xv, __uint_as_float(wb.x & 0xFFFF0000u), s[5]);
      s[6] = fmaf(xv, __uint_as_float(wb.y << 16), s[6]);
      s[7] = fmaf(xv, __uint_as_float(wb.y & 0xFFFF0000u), s[7]);
      s[8] = fmaf(xv, __uint_as_float(wcv << 16), s[8]);
    }
    #pragma unroll
    for (int l = 0; l < 9; ++l) atomicAdd(&sAcc[r * 9 + l], s[l]);
  }
  __syncthreads();

  // finalize: +b2, write logits and wsE (exp, transposed [t][j][b])
  {
    int bb = row0 >> 9, t0g = row0 & 511;
    for (int v = tid; v < 576; v += 256) {
      int r = v / 9, l = v - r * 9;
      float val = sAcc[v] + b2[l];
      logits[(size_t)(row0 + r) * 9 + l] = val;
      wsE[(size_t)((t0g + r) * 9 + l) * 64 + bb] = __expf(val);
    }
  }
}

// ---------- CRF chunk matrices: 64 chunks x 8 steps, exp-domain with rescale ----------
#define NCH 64
#define CHL 8
__global__ void crf_chunks(const float* __restrict__ wsE, const unsigned* __restrict__ wsTag,
                           const float* __restrict__ logits, const float* __restrict__ trans,
                           float* __restrict__ wsG)
{
  __shared__ float sT[81];
  int tid = threadIdx.x;
  if (tid < 81) sT[tid] = trans[tid];
  __syncthreads();
  int b = tid & 63;
  int c = blockIdx.x * 4 + (tid >> 6);

  float eT[81];
  #pragma unroll
  for (int i = 0; i < 81; ++i) eT[i] = __expf(sT[i]);

  float G[81];
  #pragma unroll
  for (int i = 0; i < 9; ++i)
    #pragma unroll
    for (int j = 0; j < 9; ++j) G[i * 9 + j] = (i == j) ? 1.f : 0.f;

  float logC = 0.f, sumN = 0.f;
  int ft = -1, lt = -1, prevL = -1;

  int tstart = c * CHL; if (c == 0) tstart = 1;
  int tend = c * CHL + CHL;

  for (int t = tstart; t < tend; ++t) {
    unsigned tv = wsTag[t * 64 + b];
    int tag = (int)(tv & 255u);
    bool m = ((tv >> 8) & 1u) != 0u;
    float E[9];
    #pragma unroll
    for (int j = 0; j < 9; ++j) E[j] = wsE[(size_t)(t * 9 + j) * 64 + b];

    // numerator partials
    float emis = logits[(size_t)b * (T_ * 9) + t * 9 + tag];
    int pidx = (prevL < 0 ? 0 : prevL) * 9 + tag;
    float trTerm = (prevL >= 0) ? sT[pidx] : 0.f;
    sumN += m ? (emis + trTerm) : 0.f;
    ft = (m && ft < 0) ? tag : ft;
    lt = m ? tag : lt;
    prevL = m ? tag : prevL;

    // G = G * (eT .* E) if masked
    #pragma unroll
    for (int i = 0; i < 9; ++i) {
      float nG[9];
      #pragma unroll
      for (int j = 0; j < 9; ++j) {
        float s = G[i * 9 + 0] * eT[j];
        #pragma unroll
        for (int k = 1; k < 9; ++k) s = fmaf(G[i * 9 + k], eT[k * 9 + j], s);
        nG[j] = s * E[j];
      }
      #pragma unroll
      for (int j = 0; j < 9; ++j) G[i * 9 + j] = m ? nG[j] : G[i * 9 + j];
    }
    // rescale (identity-safe)
    float mx = G[0];
    #pragma unroll
    for (int e = 1; e < 81; ++e) mx = fmaxf(mx, G[e]);
    float rv = 1.0f / mx;
    logC += __logf(mx);
    #pragma unroll
    for (int e = 0; e < 81; ++e) G[e] *= rv;
  }

  float* o = wsG + (size_t)c * 88 * 64 + b;
  #pragma unroll
  for (int e = 0; e < 81; ++e) o[e * 64] = G[e];
  o[81 * 64] = logC;
  o[82 * 64] = sumN;
  o[83 * 64] = __int_as_float(ft);
  o[84 * 64] = __int_as_float(lt);
}

// ---------- combine: fold 64 chunk matrices + numerator + loss ----------
__global__ void crf_combine(const float* __restrict__ wsE, const unsigned* __restrict__ wsTag,
                            const float* __restrict__ logits,
                            const float* __restrict__ start_t, const float* __restrict__ end_t,
                            const float* __restrict__ trans, const float* __restrict__ wsG,
                            float* __restrict__ out_loss)
{
  __shared__ float sT[81];
  int b = threadIdx.x;  // 64
  for (int i = b; i < 81; i += 64) sT[i] = trans[i];
  __syncthreads();

  unsigned tv0 = wsTag[b];
  int tag0 = (int)(tv0 & 255u);
  float num = start_t[tag0] + logits[(size_t)b * (T_ * 9) + tag0];
  int prev = tag0;

  float P[9];
  #pragma unroll
  for (int j = 0; j < 9; ++j) P[j] = __expf(start_t[j]) * wsE[j * 64 + b];
  float mx = P[0];
  #pragma unroll
  for (int j = 1; j < 9; ++j) mx = fmaxf(mx, P[j]);
  float C = __logf(mx);
  float rv = 1.0f / mx;
  #pragma unroll
  for (int j = 0; j < 9; ++j) P[j] *= rv;

  for (int c = 0; c < NCH; ++c) {
    const float* g = wsG + (size_t)c * 88 * 64 + b;
    float Gm[81];
    #pragma unroll
    for (int e = 0; e < 81; ++e) Gm[e] = g[e * 64];
    float logC = g[81 * 64];
    float sumN = g[82 * 64];
    int ft = __float_as_int(g[83 * 64]);
    int lt = __float_as_int(g[84 * 64]);

    float nP[9];
    #pragma unroll
    for (int j = 0; j < 9; ++j) {
      float s = P[0] * Gm[j];
      #pragma unroll
      for (int i = 1; i < 9; ++i) s = fmaf(P[i], Gm[i * 9 + j], s);
      nP[j] = s;
    }
    float mxs = nP[0];
    #pragma unroll
    for (int j = 1; j < 9; ++j) mxs = fmaxf(mxs, nP[j]);
    float rvs = 1.0f / mxs;
    C += logC + __logf(mxs);
    #pragma unroll
    for (int j = 0; j < 9; ++j) P[j] = nP[j] * rvs;

    if (ft >= 0) {
      num += sumN + sT[prev * 9 + ft];
      prev = lt;
    }
  }

  float sfin = 0.f;
  #pragma unroll
  for (int j = 0; j < 9; ++j) sfin = fmaf(P[j], __expf(end_t[j]), sfin);
  float den = C + __logf(sfin);
  num += end_t[prev];
  float d = num - den;
  #pragma unroll
  for (int off = 32; off > 0; off >>= 1) d += __shfl_down(d, off);
  if (b == 0) out_loss[0] = -d * (1.0f / 64.0f);
}

extern "C" void kernel_launch(void* const* d_in, const int* in_sizes, int n_in,
                              void* d_out, int out_size, void* d_ws, size_t ws_size,
                              hipStream_t stream) {
  (void)in_sizes; (void)n_in; (void)out_size; (void)ws_size;
  const float* hs     = (const float*)d_in[0];
  const int*   am     = (const int*)  d_in[1];
  const int*   labels = (const int*)  d_in[2];
  const float* w1     = (const float*)d_in[3];
  const float* b1     = (const float*)d_in[4];
  const float* w2     = (const float*)d_in[5];
  const float* b2     = (const float*)d_in[6];
  const float* st     = (const float*)d_in[7];
  const float* en     = (const float*)d_in[8];
  const float* tr     = (const float*)d_in[9];
  float* out = (float*)d_out;

  unsigned short* wsBn  = (unsigned short*)d_ws;                       // 1 MB
  float*          wsE   = (float*)((char*)d_ws + 1048576);             // 1.18 MB
  unsigned*       wsTag = (unsigned*)((char*)d_ws + 1048576 + 1179648);
  float*          wsG   = (float*)((char*)d_ws + 1048576 + 1179648 + 131072);

  conv_w1    <<<512, 256, 0, stream>>>(w1, wsBn);
  prep_tag   <<<128, 256, 0, stream>>>(labels, am, wsTag);
  gemm1      <<<512, 256, 0, stream>>>(hs, wsBn, b1, w2, b2, out, wsE);
  crf_chunks <<<16,  256, 0, stream>>>(wsE, wsTag, out, tr, wsG);
  crf_combine<<<1,   64,  0, stream>>>(wsE, wsTag, out, st, en, tr, wsG, out + 294912);
}

// Round 3
// 336.646 us; speedup vs baseline: 2.3916x; 1.7186x over previous
//
#include <hip/hip_runtime.h>
#include <hip/hip_bf16.h>

#define B_  64
#define T_  512
#define H_  1024
#define HC  512
#define L9  9

typedef short short8 __attribute__((ext_vector_type(8)));
typedef float f32x16 __attribute__((ext_vector_type(16)));

__device__ __forceinline__ unsigned short f2bf(float x) {
  unsigned u = __float_as_uint(x);
  u += 0x7FFFu + ((u >> 16) & 1u);   // RTNE
  return (unsigned short)(u >> 16);
}
__device__ __forceinline__ float bf2f(unsigned short h) {
  return __uint_as_float(((unsigned)h) << 16);
}

__device__ __forceinline__ void gload_lds16(const void* g, void* l) {
  __builtin_amdgcn_global_load_lds((const __attribute__((address_space(1))) unsigned*)g,
                                   (__attribute__((address_space(3))) unsigned*)l, 16, 0, 0);
}

// ---------- w1 [1024][512] fp32 -> wsBn [512][1024] bf16 (transposed) ----------
__global__ void conv_w1(const float* __restrict__ w1, unsigned short* __restrict__ w1b) {
  int idx = blockIdx.x * 256 + threadIdx.x;   // 131072 exact
  int n = idx & 511, kq = idx >> 9;           // kq 0..255
  float x0 = w1[(kq * 4 + 0) * HC + n];
  float x1 = w1[(kq * 4 + 1) * HC + n];
  float x2 = w1[(kq * 4 + 2) * HC + n];
  float x3 = w1[(kq * 4 + 3) * HC + n];
  uint2 d;
  d.x = (unsigned)f2bf(x0) | ((unsigned)f2bf(x1) << 16);
  d.y = (unsigned)f2bf(x2) | ((unsigned)f2bf(x3) << 16);
  *(uint2*)(w1b + n * 1024 + kq * 4) = d;
}

// ---------- fused GEMM: BM=64, BN=512(full), BK=64, 4 waves, 32x32x16 MFMA ----------
// epilogue: x=relu(.+b1) -> LDS, then x@W2+b2 -> logits (d_out) and exp -> wsE
__global__ __launch_bounds__(256, 2) void gemm1(
    const float* __restrict__ hs, const unsigned short* __restrict__ w1b,
    const float* __restrict__ b1, const float* __restrict__ w2,
    const float* __restrict__ b2, float* __restrict__ logits, float* __restrict__ wsE)
{
  __shared__ __align__(16) unsigned char smem[80128];
  unsigned short* ldsA = (unsigned short*)smem;            // [64][64] bf16 swizzled (8 KB)
  unsigned short* ldsB = (unsigned short*)(smem + 8192);   // [512][64] bf16 swizzled (64 KB)

  const int tid  = threadIdx.x;
  const int lane = tid & 63;
  const int w    = tid >> 6;              // wave id = wc (0..3)
  const int row0 = blockIdx.x * 64;

  f32x16 acc[2][4];
  #pragma unroll
  for (int m = 0; m < 2; ++m)
    #pragma unroll
    for (int n = 0; n < 4; ++n)
      #pragma unroll
      for (int e = 0; e < 16; ++e) acc[m][n][e] = 0.f;

  // A staging map: thread -> (row, 16-float chunk)
  const int arow = tid >> 2;
  const int aj4  = tid & 3;
  const float* aSrc = hs + (size_t)(row0 + arow) * H_ + aj4 * 16;
  unsigned short* aDst0 = ldsA + arow * 64 + (((aj4 * 2 + 0) ^ (arow & 7)) * 8);
  unsigned short* aDst1 = ldsA + arow * 64 + (((aj4 * 2 + 1) ^ (arow & 7)) * 8);

  // B staging map (pre-swizzled source, linear LDS dest)
  const int bn   = lane >> 3;                       // 0..7 row-in-chunk
  const int bjsw = ((lane & 7) ^ bn) * 8;           // swizzled source k-offset (elems)

  for (int kt = 0; kt < 16; ++kt) {
    const int k0 = kt * 64;
    // A: fp32 load -> bf16 -> swizzled ds_write
    float4 v0 = *(const float4*)(aSrc + k0);
    float4 v1 = *(const float4*)(aSrc + k0 + 4);
    float4 v2 = *(const float4*)(aSrc + k0 + 8);
    float4 v3 = *(const float4*)(aSrc + k0 + 12);
    uint4 p0, p1;
    p0.x = (unsigned)f2bf(v0.x) | ((unsigned)f2bf(v0.y) << 16);
    p0.y = (unsigned)f2bf(v0.z) | ((unsigned)f2bf(v0.w) << 16);
    p0.z = (unsigned)f2bf(v1.x) | ((unsigned)f2bf(v1.y) << 16);
    p0.w = (unsigned)f2bf(v1.z) | ((unsigned)f2bf(v1.w) << 16);
    p1.x = (unsigned)f2bf(v2.x) | ((unsigned)f2bf(v2.y) << 16);
    p1.y = (unsigned)f2bf(v2.z) | ((unsigned)f2bf(v2.w) << 16);
    p1.z = (unsigned)f2bf(v3.x) | ((unsigned)f2bf(v3.y) << 16);
    p1.w = (unsigned)f2bf(v3.z) | ((unsigned)f2bf(v3.w) << 16);
    *(uint4*)aDst0 = p0;
    *(uint4*)aDst1 = p1;
    // B: async global->LDS, 16 chunks of 1KB per wave
    #pragma unroll
    for (int i = 0; i < 16; ++i) {
      int cc = w * 16 + i;
      gload_lds16(w1b + (size_t)(cc * 8 + bn) * 1024 + k0 + bjsw,
                  (unsigned char*)ldsB + cc * 1024);
    }
    __syncthreads();
    #pragma unroll
    for (int ks = 0; ks < 4; ++ks) {
      const int blk = (((ks * 2 + (lane >> 5)) ^ (lane & 7)) * 8);
      short8 aF[2], bF[4];
      #pragma unroll
      for (int m = 0; m < 2; ++m)
        aF[m] = *(const short8*)(ldsA + (m * 32 + (lane & 31)) * 64 + blk);
      #pragma unroll
      for (int n = 0; n < 4; ++n)
        bF[n] = *(const short8*)(ldsB + (w * 128 + n * 32 + (lane & 31)) * 64 + blk);
      #pragma unroll
      for (int m = 0; m < 2; ++m)
        #pragma unroll
        for (int n = 0; n < 4; ++n)
          acc[m][n] = __builtin_amdgcn_mfma_f32_32x32x16_bf16(aF[m], bF[n], acc[m][n], 0, 0, 0);
    }
    __syncthreads();
  }

  // ---- epilogue: x = relu(acc + b1) -> LDS X [512 col][64 row] bf16, XOR-swizzled ----
  float b1v[4];
  #pragma unroll
  for (int n = 0; n < 4; ++n) b1v[n] = b1[w * 128 + n * 32 + (lane & 31)];

  #pragma unroll
  for (int m = 0; m < 2; ++m)
    #pragma unroll
    for (int n = 0; n < 4; ++n) {
      int col = w * 128 + n * 32 + (lane & 31);
      int csw = col & 7;
      unsigned char* cbase = smem + col * 128 + (lane >> 5) * 8;
      #pragma unroll
      for (int q = 0; q < 4; ++q) {
        unsigned short h0 = f2bf(fmaxf(acc[m][n][q * 4 + 0] + b1v[n], 0.f));
        unsigned short h1 = f2bf(fmaxf(acc[m][n][q * 4 + 1] + b1v[n], 0.f));
        unsigned short h2 = f2bf(fmaxf(acc[m][n][q * 4 + 2] + b1v[n], 0.f));
        unsigned short h3 = f2bf(fmaxf(acc[m][n][q * 4 + 3] + b1v[n], 0.f));
        uint2 d;
        d.x = (unsigned)h0 | ((unsigned)h1 << 16);
        d.y = (unsigned)h2 | ((unsigned)h3 << 16);
        *(uint2*)(cbase + (((4 * m + q) ^ csw) * 16)) = d;
      }
    }

  // W2 -> LDS bf16 [512][12], zero sAcc
  unsigned short* ldsW2 = (unsigned short*)(smem + 65536);
  float* sAcc = (float*)(smem + 77824);   // [64][9]
  {
    int c0 = tid * 2;
    #pragma unroll
    for (int cc = c0; cc < c0 + 2; ++cc)
      #pragma unroll
      for (int l = 0; l < 9; ++l) ldsW2[cc * 12 + l] = f2bf(w2[cc * 9 + l]);
    for (int i = tid; i < 576; i += 256) sAcc[i] = 0.f;
  }
  __syncthreads();

  // partial x@W2 per (row, col-chunk)
  {
    int r = tid & 63, ch = tid >> 6;
    int rblk = r >> 3, rlow = r & 7;
    float s[9];
    #pragma unroll
    for (int l = 0; l < 9; ++l) s[l] = 0.f;
    for (int c = ch * 128; c < ch * 128 + 128; ++c) {
      float xv = bf2f(*(const unsigned short*)(smem + c * 128 + ((rblk ^ (c & 7)) * 16) + rlow * 2));
      uint2 wa = *(const uint2*)(ldsW2 + c * 12);
      uint2 wb = *(const uint2*)(ldsW2 + c * 12 + 4);
      unsigned wcv = *(const unsigned*)(ldsW2 + c * 12 + 8);
      s[0] = fmaf(xv, __uint_as_float(wa.x << 16), s[0]);
      s[1] = fmaf(xv, __uint_as_float(wa.x & 0xFFFF0000u), s[1]);
      s[2] = fmaf(xv, __uint_as_float(wa.y << 16), s[2]);
      s[3] = fmaf(xv, __uint_as_float(wa.y & 0xFFFF0000u), s[3]);
      s[4] = fmaf(xv, __uint_as_float(wb.x << 16), s[4]);
      s[5] = fmaf(xv, __uint_as_float(wb.x & 0xFFFF0000u), s[5]);
      s[6] = fmaf(xv, __uint_as_float(wb.y << 16), s[6]);
      s[7] = fmaf(xv, __uint_as_float(wb.y & 0xFFFF0000u), s[7]);
      s[8] = fmaf(xv, __uint_as_float(wcv << 16), s[8]);
    }
    #pragma unroll
    for (int l = 0; l < 9; ++l) atomicAdd(&sAcc[r * 9 + l], s[l]);
  }
  __syncthreads();

  // finalize: +b2, write logits and wsE (exp, transposed [t][j][b])
  {
    int bb = row0 >> 9, t0g = row0 & 511;
    for (int v = tid; v < 576; v += 256) {
      int r = v / 9, l = v - r * 9;
      float val = sAcc[v] + b2[l];
      logits[(size_t)(row0 + r) * 9 + l] = val;
      wsE[(size_t)((t0g + r) * 9 + l) * 64 + bb] = __expf(val);
    }
  }
}

// ---------- CRF chunk matrices: 64 chunks x 8 steps, exp-domain with rescale ----------
// one block (64 threads = batch) per chunk; big VGPR budget so G[81]+eT[81] stay in regs
#define NCH 64
#define CHL 8
__global__ __launch_bounds__(64, 1) void crf_chunks(
    const float* __restrict__ wsE, const int* __restrict__ labels,
    const int* __restrict__ amask, const float* __restrict__ logits,
    const float* __restrict__ trans, float* __restrict__ wsG)
{
  __shared__ float sT[81];
  int b = threadIdx.x;   // 64 threads, lane = batch
  for (int i = b; i < 81; i += 64) sT[i] = trans[i];
  __syncthreads();
  int c = blockIdx.x;

  float eT[81];
  #pragma unroll
  for (int i = 0; i < 81; ++i) eT[i] = __expf(sT[i]);

  float G[81];
  #pragma unroll
  for (int i = 0; i < 9; ++i)
    #pragma unroll
    for (int j = 0; j < 9; ++j) G[i * 9 + j] = (i == j) ? 1.f : 0.f;

  float logC = 0.f, sumN = 0.f;
  int ft = -1, lt = -1, prevL = -1;

  int tstart = (c == 0) ? 1 : c * CHL;
  int tend = c * CHL + CHL;

  for (int t = tstart; t < tend; ++t) {
    int lab = labels[b * T_ + t];
    int am  = amask[b * T_ + t];
    bool valid = (lab != -100);
    int tag = valid ? lab : 0;
    bool m = (am != 0) && valid;   // t>=1 always here

    float E[9];
    #pragma unroll
    for (int j = 0; j < 9; ++j) E[j] = wsE[(size_t)(t * 9 + j) * 64 + b];

    // numerator partials
    float emis = logits[(size_t)b * (T_ * 9) + t * 9 + tag];
    int pidx = (prevL < 0 ? 0 : prevL) * 9 + tag;
    float trTerm = (prevL >= 0) ? sT[pidx] : 0.f;
    sumN += m ? (emis + trTerm) : 0.f;
    ft = (m && ft < 0) ? tag : ft;
    lt = m ? tag : lt;
    prevL = m ? tag : prevL;

    // G = G * (eT .* diag(E)) if masked  (row i depends only on row i)
    #pragma unroll
    for (int i = 0; i < 9; ++i) {
      float nG[9];
      #pragma unroll
      for (int j = 0; j < 9; ++j) {
        float s = G[i * 9 + 0] * eT[j];
        #pragma unroll
        for (int k = 1; k < 9; ++k) s = fmaf(G[i * 9 + k], eT[k * 9 + j], s);
        nG[j] = s * E[j];
      }
      #pragma unroll
      for (int j = 0; j < 9; ++j) G[i * 9 + j] = m ? nG[j] : G[i * 9 + j];
    }
    // rescale (identity-safe)
    float mx = G[0];
    #pragma unroll
    for (int e = 1; e < 81; ++e) mx = fmaxf(mx, G[e]);
    float rv = 1.0f / mx;
    logC += __logf(mx);
    #pragma unroll
    for (int e = 0; e < 81; ++e) G[e] *= rv;
  }

  float* o = wsG + (size_t)c * 88 * 64 + b;
  #pragma unroll
  for (int e = 0; e < 81; ++e) o[e * 64] = G[e];
  o[81 * 64] = logC;
  o[82 * 64] = sumN;
  o[83 * 64] = __int_as_float(ft);
  o[84 * 64] = __int_as_float(lt);
}

// ---------- combine: fold 64 chunk matrices + numerator + loss ----------
__global__ __launch_bounds__(64, 1) void crf_combine(
    const float* __restrict__ wsE, const int* __restrict__ labels,
    const float* __restrict__ logits,
    const float* __restrict__ start_t, const float* __restrict__ end_t,
    const float* __restrict__ trans, const float* __restrict__ wsG,
    float* __restrict__ out_loss)
{
  __shared__ float sT[81];
  int b = threadIdx.x;  // 64
  for (int i = b; i < 81; i += 64) sT[i] = trans[i];
  __syncthreads();

  int lab0 = labels[b * T_];
  int tag0 = (lab0 != -100) ? lab0 : 0;
  float num = start_t[tag0] + logits[(size_t)b * (T_ * 9) + tag0];
  int prev = tag0;

  float P[9];
  #pragma unroll
  for (int j = 0; j < 9; ++j) P[j] = __expf(start_t[j]) * wsE[j * 64 + b];
  float mx = P[0];
  #pragma unroll
  for (int j = 1; j < 9; ++j) mx = fmaxf(mx, P[j]);
  float C = __logf(mx);
  float rv = 1.0f / mx;
  #pragma unroll
  for (int j = 0; j < 9; ++j) P[j] *= rv;

  for (int c = 0; c < NCH; ++c) {
    const float* g = wsG + (size_t)c * 88 * 64 + b;
    float Gm[81];
    #pragma unroll
    for (int e = 0; e < 81; ++e) Gm[e] = g[e * 64];
    float logC = g[81 * 64];
    float sumN = g[82 * 64];
    int ft = __float_as_int(g[83 * 64]);
    int lt = __float_as_int(g[84 * 64]);

    float nP[9];
    #pragma unroll
    for (int j = 0; j < 9; ++j) {
      float s = P[0] * Gm[j];
      #pragma unroll
      for (int i = 1; i < 9; ++i) s = fmaf(P[i], Gm[i * 9 + j], s);
      nP[j] = s;
    }
    float mxs = nP[0];
    #pragma unroll
    for (int j = 1; j < 9; ++j) mxs = fmaxf(mxs, nP[j]);
    float rvs = 1.0f / mxs;
    C += logC + __logf(mxs);
    #pragma unroll
    for (int j = 0; j < 9; ++j) P[j] = nP[j] * rvs;

    if (ft >= 0) {
      num += sumN + sT[prev * 9 + ft];
      prev = lt;
    }
  }

  float sfin = 0.f;
  #pragma unroll
  for (int j = 0; j < 9; ++j) sfin = fmaf(P[j], __expf(end_t[j]), sfin);
  float den = C + __logf(sfin);
  num += end_t[prev];
  float d = num - den;
  #pragma unroll
  for (int off = 32; off > 0; off >>= 1) d += __shfl_down(d, off);
  if (b == 0) out_loss[0] = -d * (1.0f / 64.0f);
}

extern "C" void kernel_launch(void* const* d_in, const int* in_sizes, int n_in,
                              void* d_out, int out_size, void* d_ws, size_t ws_size,
                              hipStream_t stream) {
  (void)in_sizes; (void)n_in; (void)out_size; (void)ws_size;
  const float* hs     = (const float*)d_in[0];
  const int*   am     = (const int*)  d_in[1];
  const int*   labels = (const int*)  d_in[2];
  const float* w1     = (const float*)d_in[3];
  const float* b1     = (const float*)d_in[4];
  const float* w2     = (const float*)d_in[5];
  const float* b2     = (const float*)d_in[6];
  const float* st     = (const float*)d_in[7];
  const float* en     = (const float*)d_in[8];
  const float* tr     = (const float*)d_in[9];
  float* out = (float*)d_out;

  unsigned short* wsBn = (unsigned short*)d_ws;                    // 1 MB
  float*          wsE  = (float*)((char*)d_ws + 1048576);          // 1.18 MB
  float*          wsG  = (float*)((char*)d_ws + 1048576 + 1179648);

  conv_w1    <<<512, 256, 0, stream>>>(w1, wsBn);
  gemm1      <<<512, 256, 0, stream>>>(hs, wsBn, b1, w2, b2, out, wsE);
  crf_chunks <<<64,  64,  0, stream>>>(wsE, labels, am, out, tr, wsG);
  crf_combine<<<1,   64,  0, stream>>>(wsE, labels, out, st, en, tr, wsG, out + 294912);
}

// Round 4
// 299.191 us; speedup vs baseline: 2.6910x; 1.1252x over previous
//
#include <hip/hip_runtime.h>

#define T_  512
#define H_  1024
#define HC  512

typedef short short8 __attribute__((ext_vector_type(8)));
typedef float f32x16 __attribute__((ext_vector_type(16)));

__device__ __forceinline__ unsigned short f2bf(float x) {
  unsigned u = __float_as_uint(x);
  u += 0x7FFFu + ((u >> 16) & 1u);   // RTNE
  return (unsigned short)(u >> 16);
}
__device__ __forceinline__ float bf2f(unsigned short h) {
  return __uint_as_float(((unsigned)h) << 16);
}
__device__ __forceinline__ unsigned cvtpk(float lo, float hi) {
  unsigned r;
  asm("v_cvt_pk_bf16_f32 %0, %1, %2" : "=v"(r) : "v"(lo), "v"(hi));
  return r;
}
__device__ __forceinline__ void gload_lds16(const void* g, void* l) {
  __builtin_amdgcn_global_load_lds((const __attribute__((address_space(1))) unsigned*)g,
                                   (__attribute__((address_space(3))) unsigned*)l, 16, 0, 0);
}

// ---------- w1 [1024 k][512 n] fp32 -> wsBn k-octet-major: [o=k/8][n][8 bf16] ----------
__global__ void conv_w1(const float* __restrict__ w1, unsigned short* __restrict__ w1b) {
  int idx = blockIdx.x * 256 + threadIdx.x;   // 65536 exact
  int n = idx & 511, o = idx >> 9;            // o 0..127
  const float* src = w1 + (size_t)(o * 8) * HC + n;
  float v[8];
  #pragma unroll
  for (int j = 0; j < 8; ++j) v[j] = src[j * HC];
  uint4 d;
  d.x = cvtpk(v[0], v[1]);
  d.y = cvtpk(v[2], v[3]);
  d.z = cvtpk(v[4], v[5]);
  d.w = cvtpk(v[6], v[7]);
  *(uint4*)(w1b + (size_t)idx * 8) = d;       // (o*512+n)*8 elems = 16B chunk
}

// ---------- fused GEMM: BM=64, BN=512, BK=32, double-buffered, counted vmcnt ----------
// LDS buffer p at p*36864: A [64 r][4 slot^][16B] = 4KB ; B [4 kg][512 c][16B] = 32KB
__global__ __launch_bounds__(256, 2) void gemm1(
    const float* __restrict__ hs, const unsigned short* __restrict__ w1b,
    const float* __restrict__ b1, const float* __restrict__ w2,
    const float* __restrict__ b2, float* __restrict__ logits, float* __restrict__ wsE)
{
  __shared__ __align__(16) unsigned char smem[80128];
  const int tid  = threadIdx.x;
  const int lane = tid & 63;
  const int w    = tid >> 6;
  const int row0 = blockIdx.x * 64;

  f32x16 acc[2][4];
  #pragma unroll
  for (int m = 0; m < 2; ++m)
    #pragma unroll
    for (int n = 0; n < 4; ++n)
      #pragma unroll
      for (int e = 0; e < 16; ++e) acc[m][n][e] = 0.f;

  // A staging: thread -> (row, k-octet). write slot XOR'd by row bits.
  const int ar  = tid >> 2;                   // 0..63
  const int akg = tid & 3;
  const float* aSrc = hs + (size_t)(row0 + ar) * H_ + akg * 8;
  const int aoff = ar * 64 + ((akg ^ ((ar >> 1) & 3)) * 16);

  // ---- prologue: stage tile 0 ----
  {
    float4 av0 = *(const float4*)(aSrc);
    float4 av1 = *(const float4*)(aSrc + 4);
    unsigned char* bbase = smem + 4096;
    #pragma unroll
    for (int i = 0; i < 8; ++i) {
      int kg = i >> 1;
      int c0 = ((i & 1) * 4 + w) * 64;
      gload_lds16(w1b + ((size_t)kg * 512 + c0 + lane) * 8, bbase + (kg * 512 + c0) * 16);
    }
    uint4 ap;
    ap.x = cvtpk(av0.x, av0.y); ap.y = cvtpk(av0.z, av0.w);
    ap.z = cvtpk(av1.x, av1.y); ap.w = cvtpk(av1.z, av1.w);
    *(uint4*)(smem + aoff) = ap;
  }

  // ---- main loop: tiles 0..30 compute, prefetch kt+1 ----
  for (int kt = 0; kt < 31; ++kt) {
    const int cur = kt & 1, nxt = cur ^ 1;
    // issue A(kt+1) to regs
    float4 av0 = *(const float4*)(aSrc + (kt + 1) * 32);
    float4 av1 = *(const float4*)(aSrc + (kt + 1) * 32 + 4);
    // issue B(kt+1) to LDS[nxt]
    {
      unsigned char* bbase = smem + nxt * 36864 + 4096;
      int o0 = (kt + 1) * 4;
      #pragma unroll
      for (int i = 0; i < 8; ++i) {
        int kg = i >> 1;
        int c0 = ((i & 1) * 4 + w) * 64;
        gload_lds16(w1b + ((size_t)(o0 + kg) * 512 + c0 + lane) * 8,
                    bbase + (kg * 512 + c0) * 16);
      }
    }
    // wait B(kt) landed (10 newest = A(kt+1)+B(kt+1) stay in flight); publish ds_writes
    asm volatile("s_waitcnt vmcnt(10) lgkmcnt(0)" ::: "memory");
    __builtin_amdgcn_s_barrier();
    __builtin_amdgcn_sched_barrier(0);
    // compute tile kt
    {
      const unsigned char* abase = smem + cur * 36864;
      const unsigned char* bbase = abase + 4096;
      #pragma unroll
      for (int ks = 0; ks < 2; ++ks) {
        const int kg = ks * 2 + (lane >> 5);
        short8 aF[2], bF[4];
        #pragma unroll
        for (int m = 0; m < 2; ++m) {
          int r = m * 32 + (lane & 31);
          aF[m] = *(const short8*)(abase + r * 64 + ((kg ^ ((r >> 1) & 3)) * 16));
        }
        #pragma unroll
        for (int n = 0; n < 4; ++n) {
          int c = w * 128 + n * 32 + (lane & 31);
          bF[n] = *(const short8*)(bbase + (kg * 512 + c) * 16);
        }
        #pragma unroll
        for (int m = 0; m < 2; ++m)
          #pragma unroll
          for (int n = 0; n < 4; ++n)
            acc[m][n] = __builtin_amdgcn_mfma_f32_32x32x16_bf16(aF[m], bF[n], acc[m][n], 0, 0, 0);
      }
    }
    // convert+write A(kt+1) (compiler inserts vmcnt(8) for av regs)
    {
      uint4 ap;
      ap.x = cvtpk(av0.x, av0.y); ap.y = cvtpk(av0.z, av0.w);
      ap.z = cvtpk(av1.x, av1.y); ap.w = cvtpk(av1.z, av1.w);
      *(uint4*)(smem + nxt * 36864 + aoff) = ap;
    }
  }
  // ---- tail: tile 31 ----
  asm volatile("s_waitcnt vmcnt(0) lgkmcnt(0)" ::: "memory");
  __builtin_amdgcn_s_barrier();
  __builtin_amdgcn_sched_barrier(0);
  {
    const unsigned char* abase = smem + 36864;   // 31&1 = 1
    const unsigned char* bbase = abase + 4096;
    #pragma unroll
    for (int ks = 0; ks < 2; ++ks) {
      const int kg = ks * 2 + (lane >> 5);
      short8 aF[2], bF[4];
      #pragma unroll
      for (int m = 0; m < 2; ++m) {
        int r = m * 32 + (lane & 31);
        aF[m] = *(const short8*)(abase + r * 64 + ((kg ^ ((r >> 1) & 3)) * 16));
      }
      #pragma unroll
      for (int n = 0; n < 4; ++n) {
        int c = w * 128 + n * 32 + (lane & 31);
        bF[n] = *(const short8*)(bbase + (kg * 512 + c) * 16);
      }
      #pragma unroll
      for (int m = 0; m < 2; ++m)
        #pragma unroll
        for (int n = 0; n < 4; ++n)
          acc[m][n] = __builtin_amdgcn_mfma_f32_32x32x16_bf16(aF[m], bF[n], acc[m][n], 0, 0, 0);
    }
  }
  __syncthreads();

  // ---- epilogue: x = relu(acc + b1) -> LDS X [512 col][64 row] bf16, XOR-swizzled ----
  float b1v[4];
  #pragma unroll
  for (int n = 0; n < 4; ++n) b1v[n] = b1[w * 128 + n * 32 + (lane & 31)];

  #pragma unroll
  for (int m = 0; m < 2; ++m)
    #pragma unroll
    for (int n = 0; n < 4; ++n) {
      int col = w * 128 + n * 32 + (lane & 31);
      int csw = col & 7;
      unsigned char* cbase = smem + col * 128 + (lane >> 5) * 8;
      #pragma unroll
      for (int q = 0; q < 4; ++q) {
        float v0 = fmaxf(acc[m][n][q * 4 + 0] + b1v[n], 0.f);
        float v1 = fmaxf(acc[m][n][q * 4 + 1] + b1v[n], 0.f);
        float v2 = fmaxf(acc[m][n][q * 4 + 2] + b1v[n], 0.f);
        float v3 = fmaxf(acc[m][n][q * 4 + 3] + b1v[n], 0.f);
        uint2 d;
        d.x = cvtpk(v0, v1);
        d.y = cvtpk(v2, v3);
        *(uint2*)(cbase + (((4 * m + q) ^ csw) * 16)) = d;
      }
    }

  // W2 -> LDS bf16 [512][12], zero sAcc
  unsigned short* ldsW2 = (unsigned short*)(smem + 65536);
  float* sAcc = (float*)(smem + 77824);   // [64][9]
  {
    int c0 = tid * 2;
    #pragma unroll
    for (int cc = c0; cc < c0 + 2; ++cc)
      #pragma unroll
      for (int l = 0; l < 9; ++l) ldsW2[cc * 12 + l] = f2bf(w2[cc * 9 + l]);
    for (int i = tid; i < 576; i += 256) sAcc[i] = 0.f;
  }
  __syncthreads();

  // partial x@W2 per (row, col-chunk)
  {
    int r = tid & 63, ch = tid >> 6;
    int rblk = r >> 3, rlow = r & 7;
    float s[9];
    #pragma unroll
    for (int l = 0; l < 9; ++l) s[l] = 0.f;
    for (int c = ch * 128; c < ch * 128 + 128; ++c) {
      float xv = bf2f(*(const unsigned short*)(smem + c * 128 + ((rblk ^ (c & 7)) * 16) + rlow * 2));
      uint2 wa = *(const uint2*)(ldsW2 + c * 12);
      uint2 wb = *(const uint2*)(ldsW2 + c * 12 + 4);
      unsigned wcv = *(const unsigned*)(ldsW2 + c * 12 + 8);
      s[0] = fmaf(xv, __uint_as_float(wa.x << 16), s[0]);
      s[1] = fmaf(xv, __uint_as_float(wa.x & 0xFFFF0000u), s[1]);
      s[2] = fmaf(xv, __uint_as_float(wa.y << 16), s[2]);
      s[3] = fmaf(xv, __uint_as_float(wa.y & 0xFFFF0000u), s[3]);
      s[4] = fmaf(xv, __uint_as_float(wb.x << 16), s[4]);
      s[5] = fmaf(xv, __uint_as_float(wb.x & 0xFFFF0000u), s[5]);
      s[6] = fmaf(xv, __uint_as_float(wb.y << 16), s[6]);
      s[7] = fmaf(xv, __uint_as_float(wb.y & 0xFFFF0000u), s[7]);
      s[8] = fmaf(xv, __uint_as_float(wcv << 16), s[8]);
    }
    #pragma unroll
    for (int l = 0; l < 9; ++l) atomicAdd(&sAcc[r * 9 + l], s[l]);
  }
  __syncthreads();

  // finalize: +b2, write logits and wsE (exp, transposed [t][j][b])
  {
    int bb = row0 >> 9, t0g = row0 & 511;
    for (int v = tid; v < 576; v += 256) {
      int r = v / 9, l = v - r * 9;
      float val = sAcc[v] + b2[l];
      logits[(size_t)(row0 + r) * 9 + l] = val;
      wsE[(size_t)((t0g + r) * 9 + l) * 64 + bb] = __expf(val);
    }
  }
}

// ---------- CRF chunk matrices: 64 chunks x 8 steps, exp-domain with rescale ----------
#define NCH 64
#define CHL 8
__global__ __launch_bounds__(64, 1) void crf_chunks(
    const float* __restrict__ wsE, const int* __restrict__ labels,
    const int* __restrict__ amask, const float* __restrict__ logits,
    const float* __restrict__ trans, float* __restrict__ wsG)
{
  __shared__ float sT[81];
  int b = threadIdx.x;
  for (int i = b; i < 81; i += 64) sT[i] = trans[i];
  __syncthreads();
  int c = blockIdx.x;

  float eT[81];
  #pragma unroll
  for (int i = 0; i < 81; ++i) eT[i] = __expf(sT[i]);

  float G[81];
  #pragma unroll
  for (int i = 0; i < 9; ++i)
    #pragma unroll
    for (int j = 0; j < 9; ++j) G[i * 9 + j] = (i == j) ? 1.f : 0.f;

  float logC = 0.f, sumN = 0.f;
  int ft = -1, lt = -1, prevL = -1;

  int tstart = (c == 0) ? 1 : c * CHL;
  int tend = c * CHL + CHL;

  for (int t = tstart; t < tend; ++t) {
    int lab = labels[b * T_ + t];
    int am  = amask[b * T_ + t];
    bool valid = (lab != -100);
    int tag = valid ? lab : 0;
    bool m = (am != 0) && valid;

    float E[9];
    #pragma unroll
    for (int j = 0; j < 9; ++j) E[j] = wsE[(size_t)(t * 9 + j) * 64 + b];

    float emis = logits[(size_t)b * (T_ * 9) + t * 9 + tag];
    int pidx = (prevL < 0 ? 0 : prevL) * 9 + tag;
    float trTerm = (prevL >= 0) ? sT[pidx] : 0.f;
    sumN += m ? (emis + trTerm) : 0.f;
    ft = (m && ft < 0) ? tag : ft;
    lt = m ? tag : lt;
    prevL = m ? tag : prevL;

    #pragma unroll
    for (int i = 0; i < 9; ++i) {
      float nG[9];
      #pragma unroll
      for (int j = 0; j < 9; ++j) {
        float s = G[i * 9 + 0] * eT[j];
        #pragma unroll
        for (int k = 1; k < 9; ++k) s = fmaf(G[i * 9 + k], eT[k * 9 + j], s);
        nG[j] = s * E[j];
      }
      #pragma unroll
      for (int j = 0; j < 9; ++j) G[i * 9 + j] = m ? nG[j] : G[i * 9 + j];
    }
    float mx = G[0];
    #pragma unroll
    for (int e = 1; e < 81; ++e) mx = fmaxf(mx, G[e]);
    float rv = 1.0f / mx;
    logC += __logf(mx);
    #pragma unroll
    for (int e = 0; e < 81; ++e) G[e] *= rv;
  }

  float* o = wsG + (size_t)c * 88 * 64 + b;
  #pragma unroll
  for (int e = 0; e < 81; ++e) o[e * 64] = G[e];
  o[81 * 64] = logC;
  o[82 * 64] = sumN;
  o[83 * 64] = __int_as_float(ft);
  o[84 * 64] = __int_as_float(lt);
}

// ---------- fold level 1: 8 blocks, each folds 8 chunk matrices ----------
__global__ __launch_bounds__(64, 1) void crf_fold(
    const float* __restrict__ wsG, const float* __restrict__ trans,
    float* __restrict__ wsG2)
{
  __shared__ float sT[81];
  int b = threadIdx.x;
  for (int i = b; i < 81; i += 64) sT[i] = trans[i];
  __syncthreads();
  int f = blockIdx.x;

  float G[81];
  #pragma unroll
  for (int i = 0; i < 9; ++i)
    #pragma unroll
    for (int j = 0; j < 9; ++j) G[i * 9 + j] = (i == j) ? 1.f : 0.f;
  float logC = 0.f, sumN = 0.f;
  int ft = -1, lt = -1;

  for (int cc = 0; cc < 8; ++cc) {
    const float* g = wsG + (size_t)(f * 8 + cc) * 88 * 64 + b;
    float Gm[81];
    #pragma unroll
    for (int e = 0; e < 81; ++e) Gm[e] = g[e * 64];
    float lC = g[81 * 64], sN = g[82 * 64];
    int fte = __float_as_int(g[83 * 64]);
    int lte = __float_as_int(g[84 * 64]);

    #pragma unroll
    for (int i = 0; i < 9; ++i) {
      float row[9];
      #pragma unroll
      for (int j = 0; j < 9; ++j) {
        float s = G[i * 9 + 0] * Gm[j];
        #pragma unroll
        for (int k = 1; k < 9; ++k) s = fmaf(G[i * 9 + k], Gm[k * 9 + j], s);
        row[j] = s;
      }
      #pragma unroll
      for (int j = 0; j < 9; ++j) G[i * 9 + j] = row[j];
    }
    float mx = G[0];
    #pragma unroll
    for (int e = 1; e < 81; ++e) mx = fmaxf(mx, G[e]);
    logC += lC + __logf(mx);
    float rv = 1.0f / mx;
    #pragma unroll
    for (int e = 0; e < 81; ++e) G[e] *= rv;

    if (fte >= 0) {
      sumN += sN + (lt >= 0 ? sT[lt * 9 + fte] : 0.f);
      if (ft < 0) ft = fte;
      lt = lte;
    }
  }

  float* o = wsG2 + (size_t)f * 88 * 64 + b;
  #pragma unroll
  for (int e = 0; e < 81; ++e) o[e * 64] = G[e];
  o[81 * 64] = logC;
  o[82 * 64] = sumN;
  o[83 * 64] = __int_as_float(ft);
  o[84 * 64] = __int_as_float(lt);
}

// ---------- final: fold 8 + start/end + loss ----------
__global__ __launch_bounds__(64, 1) void crf_final(
    const float* __restrict__ wsE, const int* __restrict__ labels,
    const float* __restrict__ logits,
    const float* __restrict__ start_t, const float* __restrict__ end_t,
    const float* __restrict__ trans, const float* __restrict__ wsG2,
    float* __restrict__ out_loss)
{
  __shared__ float sT[81];
  int b = threadIdx.x;
  for (int i = b; i < 81; i += 64) sT[i] = trans[i];
  __syncthreads();

  int lab0 = labels[b * T_];
  int tag0 = (lab0 != -100) ? lab0 : 0;
  float num = start_t[tag0] + logits[(size_t)b * (T_ * 9) + tag0];
  int prev = tag0;

  float P[9];
  #pragma unroll
  for (int j = 0; j < 9; ++j) P[j] = __expf(start_t[j]) * wsE[j * 64 + b];
  float mx = P[0];
  #pragma unroll
  for (int j = 1; j < 9; ++j) mx = fmaxf(mx, P[j]);
  float C = __logf(mx);
  float rv = 1.0f / mx;
  #pragma unroll
  for (int j = 0; j < 9; ++j) P[j] *= rv;

  for (int c = 0; c < 8; ++c) {
    const float* g = wsG2 + (size_t)c * 88 * 64 + b;
    float Gm[81];
    #pragma unroll
    for (int e = 0; e < 81; ++e) Gm[e] = g[e * 64];
    float logC = g[81 * 64];
    float sumN = g[82 * 64];
    int ft = __float_as_int(g[83 * 64]);
    int lt = __float_as_int(g[84 * 64]);

    float nP[9];
    #pragma unroll
    for (int j = 0; j < 9; ++j) {
      float s = P[0] * Gm[j];
      #pragma unroll
      for (int i = 1; i < 9; ++i) s = fmaf(P[i], Gm[i * 9 + j], s);
      nP[j] = s;
    }
    float mxs = nP[0];
    #pragma unroll
    for (int j = 1; j < 9; ++j) mxs = fmaxf(mxs, nP[j]);
    float rvs = 1.0f / mxs;
    C += logC + __logf(mxs);
    #pragma unroll
    for (int j = 0; j < 9; ++j) P[j] = nP[j] * rvs;

    if (ft >= 0) {
      num += sumN + sT[prev * 9 + ft];
      prev = lt;
    }
  }

  float sfin = 0.f;
  #pragma unroll
  for (int j = 0; j < 9; ++j) sfin = fmaf(P[j], __expf(end_t[j]), sfin);
  float den = C + __logf(sfin);
  num += end_t[prev];
  float d = num - den;
  #pragma unroll
  for (int off = 32; off > 0; off >>= 1) d += __shfl_down(d, off);
  if (b == 0) out_loss[0] = -d * (1.0f / 64.0f);
}

extern "C" void kernel_launch(void* const* d_in, const int* in_sizes, int n_in,
                              void* d_out, int out_size, void* d_ws, size_t ws_size,
                              hipStream_t stream) {
  (void)in_sizes; (void)n_in; (void)out_size; (void)ws_size;
  const float* hs     = (const float*)d_in[0];
  const int*   am     = (const int*)  d_in[1];
  const int*   labels = (const int*)  d_in[2];
  const float* w1     = (const float*)d_in[3];
  const float* b1     = (const float*)d_in[4];
  const float* w2     = (const float*)d_in[5];
  const float* b2     = (const float*)d_in[6];
  const float* st     = (const float*)d_in[7];
  const float* en     = (const float*)d_in[8];
  const float* tr     = (const float*)d_in[9];
  float* out = (float*)d_out;

  unsigned short* wsBn = (unsigned short*)d_ws;                     // 1 MB
  float*          wsE  = (float*)((char*)d_ws + 1048576);           // 1.18 MB
  float*          wsG  = (float*)((char*)d_ws + 2228224);           // 1.44 MB
  float*          wsG2 = (float*)((char*)d_ws + 3670016);           // 176 KB

  conv_w1   <<<256, 256, 0, stream>>>(w1, wsBn);
  gemm1     <<<512, 256, 0, stream>>>(hs, wsBn, b1, w2, b2, out, wsE);
  crf_chunks<<<64,  64,  0, stream>>>(wsE, labels, am, out, tr, wsG);
  crf_fold  <<<8,   64,  0, stream>>>(wsG, tr, wsG2);
  crf_final <<<1,   64,  0, stream>>>(wsE, labels, out, st, en, tr, wsG2, out + 294912);
}